// Round 2
// baseline (11417.585 us; speedup 1.0000x reference)
//
#include <hip/hip_runtime.h>

typedef unsigned int uint;

#define SQ_   2048
#define SK_   2048
#define NB    8
#define DD    1024
#define INNER 128
#define H_    4
#define HD    32
#define TK    128

// ---------------------------------------------------------------------------
// Kernel 1: QKV projections (fp32).  blockIdx.y: 0=q(from query), 1=k, 2=v.
// One block per seq position s; its 8 batch rows (32 KB fp32) staged in LDS;
// 128 threads each own one output channel e = h*32+c and dot 1024 for all 8 n.
// Output layout: dst[((n*H + h)*2048 + s)*32 + c]   (fp32)
// ---------------------------------------------------------------------------
__global__ __launch_bounds__(128) void proj_kernel(
    const float* __restrict__ query, const float* __restrict__ key_feat,
    const float* __restrict__ Wq, const float* __restrict__ Wk, const float* __restrict__ Wv,
    float* __restrict__ q_ws, float* __restrict__ k_ws, float* __restrict__ v_ws)
{
    const int which = blockIdx.y;
    const float* src = (which == 0) ? query : key_feat;
    const float* W   = (which == 0) ? Wq : (which == 1) ? Wk : Wv;
    float* dst       = (which == 0) ? q_ws : (which == 1) ? k_ws : v_ws;

    const int s = blockIdx.x;
    __shared__ float rows[NB * DD];          // 32 KB, 8 rows fp32
    const float4* src4 = (const float4*)(src + (size_t)s * NB * DD);
    float4* rows4 = (float4*)rows;
    for (int i = threadIdx.x; i < NB * DD / 4; i += 128)
        rows4[i] = src4[i];
    __syncthreads();

    const int e = threadIdx.x;
    const int h = e >> 5, c = e & 31;
    const float4* w4 = (const float4*)(W + (size_t)e * DD);
    float acc[NB];
#pragma unroll
    for (int p = 0; p < NB; p++) acc[p] = 0.f;

    for (int i = 0; i < DD / 8; i++) {
        float4 wa = w4[i * 2], wb = w4[i * 2 + 1];
#pragma unroll
        for (int p = 0; p < NB; p++) {
            const float4* r = (const float4*)&rows[p * DD + i * 8];
            float4 r0 = r[0], r1 = r[1];
            acc[p] = fmaf(wa.x, r0.x, fmaf(wa.y, r0.y, fmaf(wa.z, r0.z, fmaf(wa.w, r0.w, acc[p]))));
            acc[p] = fmaf(wb.x, r1.x, fmaf(wb.y, r1.y, fmaf(wb.z, r1.z, fmaf(wb.w, r1.w, acc[p]))));
        }
    }
#pragma unroll
    for (int p = 0; p < NB; p++)
        dst[(((size_t)(p * H_ + h)) * 2048 + s) * HD + c] = acc[p];
}

// ---------------------------------------------------------------------------
// Kernel 2: attention (fp32).  One block = 128 threads = 128 q rows of one
// (n,h); each lane owns one q row (q, o, l in registers).  K/V staged in LDS,
// TK=128 keys per tile.  No max subtraction: |score| <= ~12, exp safe in fp32.
// Output: x_ws[(n*2048 + s)*128 + h*32 + c]   (fp32)
// ---------------------------------------------------------------------------
__global__ __launch_bounds__(128) void attn_kernel(
    const float* __restrict__ q_ws, const float* __restrict__ k_ws,
    const float* __restrict__ v_ws, float* __restrict__ x_ws)
{
    const int nh = blockIdx.x >> 4;            // 16 blocks per (n,h)
    const int srow = ((blockIdx.x & 15) << 7) + threadIdx.x;

    __shared__ float kS[TK * HD];              // 16 KB
    __shared__ float vS[TK * HD];              // 16 KB

    const float scale = 0.17677669529663687f;  // 1/sqrt(32)
    float qv[HD];
    {
        const float4* q4 = (const float4*)(q_ws + ((size_t)nh * SQ_ + srow) * HD);
#pragma unroll
        for (int i = 0; i < 8; i++) {
            float4 u = q4[i];
            qv[i*4+0] = u.x * scale; qv[i*4+1] = u.y * scale;
            qv[i*4+2] = u.z * scale; qv[i*4+3] = u.w * scale;
        }
    }
    float o[HD];
#pragma unroll
    for (int c = 0; c < HD; c++) o[c] = 0.f;
    float l = 0.f;

    for (int t = 0; t < SK_ / TK; t++) {
        __syncthreads();
        const float4* ks4 = (const float4*)(k_ws + ((size_t)nh * SK_ + t * TK) * HD);
        const float4* vs4 = (const float4*)(v_ws + ((size_t)nh * SK_ + t * TK) * HD);
        float4* kd = (float4*)kS;
        float4* vd = (float4*)vS;
        for (int i = threadIdx.x; i < TK * HD / 4; i += 128) {
            kd[i] = ks4[i];
            vd[i] = vs4[i];
        }
        __syncthreads();

        for (int kk = 0; kk < TK; kk++) {
            float a0 = 0.f, a1 = 0.f, a2 = 0.f, a3 = 0.f;
#pragma unroll
            for (int c = 0; c < HD; c += 4) {
                float4 kf = *(const float4*)&kS[kk * HD + c];
                a0 = fmaf(qv[c+0], kf.x, a0);
                a1 = fmaf(qv[c+1], kf.y, a1);
                a2 = fmaf(qv[c+2], kf.z, a2);
                a3 = fmaf(qv[c+3], kf.w, a3);
            }
            float p = __expf((a0 + a1) + (a2 + a3));
            l += p;
#pragma unroll
            for (int c = 0; c < HD; c += 4) {
                float4 vf = *(const float4*)&vS[kk * HD + c];
                o[c+0] = fmaf(p, vf.x, o[c+0]);
                o[c+1] = fmaf(p, vf.y, o[c+1]);
                o[c+2] = fmaf(p, vf.z, o[c+2]);
                o[c+3] = fmaf(p, vf.w, o[c+3]);
            }
        }
    }

    const float invl = 1.f / l;
    const int n = nh >> 2, h = nh & 3;
    float* xo = x_ws + (((size_t)n * SQ_ + srow) * INNER + h * HD);
#pragma unroll
    for (int c = 0; c < HD; c++)
        xo[c] = o[c] * invl;
}

// ---------------------------------------------------------------------------
// Kernel 3: up-projection (fp32).  out[(s*8+n)*1024 + d] = sum_e x[n][s][e]*Wup[d][e].
// One block per s: 8 x-rows (4 KB) staged in LDS; 256 threads x 4 d's each;
// each Wup row read once per block, reused for all 8 n.
// ---------------------------------------------------------------------------
__global__ __launch_bounds__(256) void up_kernel(
    const float* __restrict__ x_ws, const float* __restrict__ Wup,
    float* __restrict__ out)
{
    const int s = blockIdx.x;
    __shared__ float xr[NB * INNER];           // 4 KB
    for (int i = threadIdx.x; i < NB * INNER; i += 256) {
        int n = i >> 7, j = i & 127;
        xr[i] = x_ws[((size_t)n * SQ_ + s) * INNER + j];
    }
    __syncthreads();

#pragma unroll
    for (int jj = 0; jj < 4; jj++) {
        const int d = threadIdx.x + 256 * jj;
        const float4* w4 = (const float4*)(Wup + (size_t)d * INNER);
        float acc[NB];
#pragma unroll
        for (int n = 0; n < NB; n++) acc[n] = 0.f;
#pragma unroll
        for (int i = 0; i < 16; i++) {
            float4 wa = w4[i * 2], wb = w4[i * 2 + 1];
#pragma unroll
            for (int n = 0; n < NB; n++) {
                const float4* r = (const float4*)&xr[n * INNER + i * 8];
                float4 r0 = r[0], r1 = r[1];
                acc[n] = fmaf(wa.x, r0.x, fmaf(wa.y, r0.y, fmaf(wa.z, r0.z, fmaf(wa.w, r0.w, acc[n]))));
                acc[n] = fmaf(wb.x, r1.x, fmaf(wb.y, r1.y, fmaf(wb.z, r1.z, fmaf(wb.w, r1.w, acc[n]))));
            }
        }
        float* orow = out + (size_t)s * NB * DD + d;
#pragma unroll
        for (int n = 0; n < NB; n++) orow[(size_t)n * DD] = acc[n];
    }
}

// ---------------------------------------------------------------------------
extern "C" void kernel_launch(void* const* d_in, const int* in_sizes, int n_in,
                              void* d_out, int out_size, void* d_ws, size_t ws_size,
                              hipStream_t stream)
{
    const float* query    = (const float*)d_in[0];
    const float* key_feat = (const float*)d_in[1];
    const float* Wq  = (const float*)d_in[2];
    const float* Wk  = (const float*)d_in[3];
    const float* Wv  = (const float*)d_in[4];
    const float* Wup = (const float*)d_in[5];
    float* out = (float*)d_out;

    float* ws = (float*)d_ws;
    const size_t SZ = (size_t)NB * H_ * 2048 * HD;   // 2,097,152 elems per tensor
    float* q_ws = ws;
    float* k_ws = ws + SZ;
    float* v_ws = ws + 2 * SZ;
    float* x_ws = ws + 3 * SZ;

    proj_kernel<<<dim3(2048, 3), 128, 0, stream>>>(query, key_feat, Wq, Wk, Wv,
                                                   q_ws, k_ws, v_ws);
    attn_kernel<<<512, 128, 0, stream>>>(q_ws, k_ws, v_ws, x_ws);
    up_kernel<<<2048, 256, 0, stream>>>(x_ws, Wup, out);
}

// Round 3
// 1820.516 us; speedup vs baseline: 6.2716x; 6.2716x over previous
//
#include <hip/hip_runtime.h>

typedef unsigned int uint;

#define SQ_   2048
#define SK_   2048
#define NB    8
#define DD    1024
#define INNER 128
#define H_    4
#define HD    32
#define TK    128

// ---------------------------------------------------------------------------
// Kernel 1: QKV projections (fp32).  blockIdx.y: 0=q(from query), 1=k, 2=v.
// One block per seq position s; its 8 batch rows (32 KB fp32) staged in LDS;
// 128 threads each own one output channel e = h*32+c and dot 1024 for all 8 n.
// Output layout: dst[((n*H + h)*2048 + s)*32 + c]   (fp32)
// ---------------------------------------------------------------------------
__global__ __launch_bounds__(128) void proj_kernel(
    const float* __restrict__ query, const float* __restrict__ key_feat,
    const float* __restrict__ Wq, const float* __restrict__ Wk, const float* __restrict__ Wv,
    float* __restrict__ q_ws, float* __restrict__ k_ws, float* __restrict__ v_ws)
{
    const int which = blockIdx.y;
    const float* src = (which == 0) ? query : key_feat;
    const float* W   = (which == 0) ? Wq : (which == 1) ? Wk : Wv;
    float* dst       = (which == 0) ? q_ws : (which == 1) ? k_ws : v_ws;

    const int s = blockIdx.x;
    __shared__ float rows[NB * DD];          // 32 KB, 8 rows fp32
    const float4* src4 = (const float4*)(src + (size_t)s * NB * DD);
    float4* rows4 = (float4*)rows;
    for (int i = threadIdx.x; i < NB * DD / 4; i += 128)
        rows4[i] = src4[i];
    __syncthreads();

    const int e = threadIdx.x;
    const int h = e >> 5, c = e & 31;
    const float4* w4 = (const float4*)(W + (size_t)e * DD);
    float acc[NB];
#pragma unroll
    for (int p = 0; p < NB; p++) acc[p] = 0.f;

    for (int i = 0; i < DD / 8; i++) {
        float4 wa = w4[i * 2], wb = w4[i * 2 + 1];
#pragma unroll
        for (int p = 0; p < NB; p++) {
            const float4* r = (const float4*)&rows[p * DD + i * 8];
            float4 r0 = r[0], r1 = r[1];
            acc[p] = fmaf(wa.x, r0.x, fmaf(wa.y, r0.y, fmaf(wa.z, r0.z, fmaf(wa.w, r0.w, acc[p]))));
            acc[p] = fmaf(wb.x, r1.x, fmaf(wb.y, r1.y, fmaf(wb.z, r1.z, fmaf(wb.w, r1.w, acc[p]))));
        }
    }
#pragma unroll
    for (int p = 0; p < NB; p++)
        dst[(((size_t)(p * H_ + h)) * 2048 + s) * HD + c] = acc[p];
}

// ---------------------------------------------------------------------------
// Kernel 2: attention (fp32).  One block = 128 threads = 128 q rows of one
// (n,h); each lane owns one q row (q, o, l in registers).  K/V staged in LDS,
// TK=128 keys per tile.  No max subtraction: |score| <= ~12, exp safe in fp32.
// Output: x_ws[(n*2048 + s)*128 + h*32 + c]   (fp32)
// ---------------------------------------------------------------------------
__global__ __launch_bounds__(128) void attn_kernel(
    const float* __restrict__ q_ws, const float* __restrict__ k_ws,
    const float* __restrict__ v_ws, float* __restrict__ x_ws)
{
    const int nh = blockIdx.x >> 4;            // 16 blocks per (n,h)
    const int srow = ((blockIdx.x & 15) << 7) + threadIdx.x;

    __shared__ float kS[TK * HD];              // 16 KB
    __shared__ float vS[TK * HD];              // 16 KB

    const float scale = 0.17677669529663687f;  // 1/sqrt(32)
    float qv[HD];
    {
        const float4* q4 = (const float4*)(q_ws + ((size_t)nh * SQ_ + srow) * HD);
#pragma unroll
        for (int i = 0; i < 8; i++) {
            float4 u = q4[i];
            qv[i*4+0] = u.x * scale; qv[i*4+1] = u.y * scale;
            qv[i*4+2] = u.z * scale; qv[i*4+3] = u.w * scale;
        }
    }
    float o[HD];
#pragma unroll
    for (int c = 0; c < HD; c++) o[c] = 0.f;
    float l = 0.f;

    for (int t = 0; t < SK_ / TK; t++) {
        __syncthreads();
        const float4* ks4 = (const float4*)(k_ws + ((size_t)nh * SK_ + t * TK) * HD);
        const float4* vs4 = (const float4*)(v_ws + ((size_t)nh * SK_ + t * TK) * HD);
        float4* kd = (float4*)kS;
        float4* vd = (float4*)vS;
        for (int i = threadIdx.x; i < TK * HD / 4; i += 128) {
            kd[i] = ks4[i];
            vd[i] = vs4[i];
        }
        __syncthreads();

        for (int kk = 0; kk < TK; kk++) {
            float a0 = 0.f, a1 = 0.f, a2 = 0.f, a3 = 0.f;
#pragma unroll
            for (int c = 0; c < HD; c += 4) {
                float4 kf = *(const float4*)&kS[kk * HD + c];
                a0 = fmaf(qv[c+0], kf.x, a0);
                a1 = fmaf(qv[c+1], kf.y, a1);
                a2 = fmaf(qv[c+2], kf.z, a2);
                a3 = fmaf(qv[c+3], kf.w, a3);
            }
            float p = __expf((a0 + a1) + (a2 + a3));
            l += p;
#pragma unroll
            for (int c = 0; c < HD; c += 4) {
                float4 vf = *(const float4*)&vS[kk * HD + c];
                o[c+0] = fmaf(p, vf.x, o[c+0]);
                o[c+1] = fmaf(p, vf.y, o[c+1]);
                o[c+2] = fmaf(p, vf.z, o[c+2]);
                o[c+3] = fmaf(p, vf.w, o[c+3]);
            }
        }
    }

    const float invl = 1.f / l;
    const int n = nh >> 2, h = nh & 3;
    float* xo = x_ws + (((size_t)n * SQ_ + srow) * INNER + h * HD);
#pragma unroll
    for (int c = 0; c < HD; c++)
        xo[c] = o[c] * invl;
}

// ---------------------------------------------------------------------------
// Kernel 3: up-projection (fp32).  out[(s*8+n)*1024 + d] = sum_e x[n][s][e]*Wup[d][e].
// One block per s: 8 x-rows (4 KB) staged in LDS; 256 threads; thread t
// handles d = t, t+256, t+512, t+768 SEQUENTIALLY (jj loop NOT unrolled —
// round-2 post-mortem: double unroll spilled to 256 VGPR + 13 GB scratch
// traffic = 9.7 ms).  Reduction loop unrolled 4x only: live set = 8 acc +
// 4 w-float4 + temps ~ <=96 VGPR, no spill.
// ---------------------------------------------------------------------------
__global__ __launch_bounds__(256) void up_kernel(
    const float* __restrict__ x_ws, const float* __restrict__ Wup,
    float* __restrict__ out)
{
    const int s = blockIdx.x;
    __shared__ float xr[NB * INNER];           // 4 KB
    for (int i = threadIdx.x; i < NB * INNER; i += 256) {
        int n = i >> 7, j = i & 127;
        xr[i] = x_ws[((size_t)n * SQ_ + s) * INNER + j];
    }
    __syncthreads();

#pragma unroll 1
    for (int jj = 0; jj < 4; jj++) {
        const int d = (jj << 8) + threadIdx.x;
        const float4* w4 = (const float4*)(Wup + (size_t)d * INNER);
        float acc[NB];
#pragma unroll
        for (int n = 0; n < NB; n++) acc[n] = 0.f;
#pragma unroll 4
        for (int i = 0; i < INNER / 4; i++) {
            float4 w = w4[i];
#pragma unroll
            for (int n = 0; n < NB; n++) {
                float4 x = *(const float4*)&xr[n * INNER + i * 4];
                acc[n] = fmaf(w.x, x.x, fmaf(w.y, x.y, fmaf(w.z, x.z, fmaf(w.w, x.w, acc[n]))));
            }
        }
        float* orow = out + (size_t)s * NB * DD + d;
#pragma unroll
        for (int n = 0; n < NB; n++) orow[(size_t)n * DD] = acc[n];
    }
}

// ---------------------------------------------------------------------------
extern "C" void kernel_launch(void* const* d_in, const int* in_sizes, int n_in,
                              void* d_out, int out_size, void* d_ws, size_t ws_size,
                              hipStream_t stream)
{
    const float* query    = (const float*)d_in[0];
    const float* key_feat = (const float*)d_in[1];
    const float* Wq  = (const float*)d_in[2];
    const float* Wk  = (const float*)d_in[3];
    const float* Wv  = (const float*)d_in[4];
    const float* Wup = (const float*)d_in[5];
    float* out = (float*)d_out;

    float* ws = (float*)d_ws;
    const size_t SZ = (size_t)NB * H_ * 2048 * HD;   // 2,097,152 elems per tensor
    float* q_ws = ws;
    float* k_ws = ws + SZ;
    float* v_ws = ws + 2 * SZ;
    float* x_ws = ws + 3 * SZ;

    proj_kernel<<<dim3(2048, 3), 128, 0, stream>>>(query, key_feat, Wq, Wk, Wv,
                                                   q_ws, k_ws, v_ws);
    attn_kernel<<<512, 128, 0, stream>>>(q_ws, k_ws, v_ws, x_ws);
    up_kernel<<<2048, 256, 0, stream>>>(x_ws, Wup, out);
}

// Round 4
// 768.461 us; speedup vs baseline: 14.8577x; 2.3690x over previous
//
#include <hip/hip_runtime.h>

typedef unsigned int uint;
typedef unsigned short ushort;
typedef float f32x4 __attribute__((ext_vector_type(4)));
typedef short bf16x8 __attribute__((ext_vector_type(8)));

#define SQ_   2048
#define SK_   2048
#define NB    8
#define DD    1024
#define INNER 128
#define H_    4
#define HD    32
#define NH_   32
// 1/sqrt(32) folded into q at projection time
#define ALPHA 0.17677669529663687f

__device__ __forceinline__ ushort f2bf(float f) {
    uint u = __float_as_uint(f);
    u += 0x7fffu + ((u >> 16) & 1u);
    return (ushort)(u >> 16);
}
__device__ __forceinline__ uint pack2(float a, float b) {
    return (uint)f2bf(a) | ((uint)f2bf(b) << 16);
}

// ---------------------------------------------------------------------------
// Kernel 1: QKV projections (fp32 compute -> bf16 out).  blockIdx.y: 0=q,1=k,2=v.
// One block per seq position s; 8 batch rows staged in LDS; 128 threads each
// own channel e=h*32+c, dot 1024 for all 8 n.  q is pre-scaled by 1/sqrt(32).
// Output: dst[((n*H + h)*2048 + s)*32 + c]  (bf16)
// ---------------------------------------------------------------------------
__global__ __launch_bounds__(128) void proj_kernel(
    const float* __restrict__ query, const float* __restrict__ key_feat,
    const float* __restrict__ Wq, const float* __restrict__ Wk, const float* __restrict__ Wv,
    ushort* __restrict__ q_ws, ushort* __restrict__ k_ws, ushort* __restrict__ v_ws)
{
    const int which = blockIdx.y;
    const float* src = (which == 0) ? query : key_feat;
    const float* W   = (which == 0) ? Wq : (which == 1) ? Wk : Wv;
    ushort* dst      = (which == 0) ? q_ws : (which == 1) ? k_ws : v_ws;
    const float oscale = (which == 0) ? ALPHA : 1.0f;

    const int s = blockIdx.x;
    __shared__ float rows[NB * DD];          // 32 KB
    const float4* src4 = (const float4*)(src + (size_t)s * NB * DD);
    float4* rows4 = (float4*)rows;
    for (int i = threadIdx.x; i < NB * DD / 4; i += 128)
        rows4[i] = src4[i];
    __syncthreads();

    const int e = threadIdx.x;
    const int h = e >> 5, c = e & 31;
    const float4* w4 = (const float4*)(W + (size_t)e * DD);
    float acc[NB];
#pragma unroll
    for (int p = 0; p < NB; p++) acc[p] = 0.f;

    for (int i = 0; i < DD / 8; i++) {
        float4 wa = w4[i * 2], wb = w4[i * 2 + 1];
#pragma unroll
        for (int p = 0; p < NB; p++) {
            const float4* r = (const float4*)&rows[p * DD + i * 8];
            float4 r0 = r[0], r1 = r[1];
            acc[p] = fmaf(wa.x, r0.x, fmaf(wa.y, r0.y, fmaf(wa.z, r0.z, fmaf(wa.w, r0.w, acc[p]))));
            acc[p] = fmaf(wb.x, r1.x, fmaf(wb.y, r1.y, fmaf(wb.z, r1.z, fmaf(wb.w, r1.w, acc[p]))));
        }
    }
#pragma unroll
    for (int p = 0; p < NB; p++)
        dst[(((size_t)(p * H_ + h)) * 2048 + s) * HD + c] = f2bf(acc[p] * oscale);
}

// ---------------------------------------------------------------------------
// Kernel 2: transpose V -> V^T.  v_ws[nh][key][32] bf16 -> vt_ws[nh][32][key].
// Block = one (nh, 128-key slab).  LDS-staged tile, coalesced in and out.
// ---------------------------------------------------------------------------
__global__ __launch_bounds__(256) void vtrans_kernel(
    const ushort* __restrict__ v_ws, ushort* __restrict__ vt_ws)
{
    const int nh = blockIdx.x >> 4;
    const int slab = blockIdx.x & 15;
    __shared__ ushort t[HD][132];            // +4 pad
    const uint* src = (const uint*)(v_ws + ((size_t)nh * SK_ + slab * 128) * HD);
#pragma unroll
    for (int it = 0; it < 8; it++) {
        int i = it * 256 + threadIdx.x;      // 2048 uints = 128 keys x 16
        int key = i >> 4, j = i & 15;
        uint u = src[i];
        t[2 * j][key]     = (ushort)(u & 0xffffu);
        t[2 * j + 1][key] = (ushort)(u >> 16);
    }
    __syncthreads();
    uint* dst = (uint*)vt_ws;
#pragma unroll
    for (int it = 0; it < 8; it++) {
        int i = it * 256 + threadIdx.x;      // 2048 uints = 32 c x 64
        int c = i >> 6, kk = (i & 63) * 2;
        dst[(size_t)(nh * HD + c) * (SK_ / 2) + slab * 64 + (i & 63)] =
            (uint)t[c][kk] | ((uint)t[c][kk + 1] << 16);
    }
}

// ---------------------------------------------------------------------------
// Kernel 3: attention via MFMA 16x16x32 bf16.  Block = 256 thr = 4 waves;
// each wave owns a 16-row q-tile of one (n,h); grid = (32 qblocks, 32 nh).
// S^T = K.Q^T  (A = K-tile contiguous, B = Q^T contiguous);
// P = exp(S) fp32 -> bf16; in-wave shuffle-permute C/D -> B-frag;
// O^T = V^T.P  (A = V^T contiguous).  No LDS, no barriers, no max-tracking
// (|score| <= ~11, exp fp32-safe; partial l-sums are additive).
// Output: x_ws[(n*2048+s)*128 + h*32 + c]  (fp32)
// ---------------------------------------------------------------------------
__global__ __launch_bounds__(256) void attn_mfma(
    const ushort* __restrict__ q_ws, const ushort* __restrict__ k_ws,
    const ushort* __restrict__ vt_ws, float* __restrict__ x_ws)
{
    const int nh   = blockIdx.y;
    const int lane = threadIdx.x & 63;
    const int wave = threadIdx.x >> 6;
    const int quad = lane >> 4;
    const int col  = lane & 15;
    const int qbase = blockIdx.x * 64 + wave * 16;

    // B-frag: Q^T [32c x 16q]: B[k=quad*8+j][n=col]
    const bf16x8 bQ = *(const bf16x8*)(q_ws + ((size_t)nh * SQ_ + qbase + col) * HD + quad * 8);

    f32x4 acc0 = {0.f, 0.f, 0.f, 0.f};
    f32x4 acc1 = {0.f, 0.f, 0.f, 0.f};
    float lsum = 0.f;

    const ushort* kb = k_ws  + (size_t)nh * SK_ * HD;
    const ushort* vb = vt_ws + (size_t)nh * HD * SK_;
    const int sA = ((quad & 1) << 5) + col;   // shuffle src lanes for P permute
    const int sB = sA + 16;
    const bool lo = quad < 2;

#pragma unroll 2
    for (int kc = 0; kc < SK_; kc += 32) {
        // A-frags: K rows (16 keys x 32 c), two 16-key tiles
        bf16x8 aK0 = *(const bf16x8*)(kb + (size_t)(kc + col) * HD + quad * 8);
        bf16x8 aK1 = *(const bf16x8*)(kb + (size_t)(kc + 16 + col) * HD + quad * 8);
        // A-frags: V^T rows (16 c x 32 keys), two c-halves
        bf16x8 aV0 = *(const bf16x8*)(vb + (size_t)col * SK_ + kc + quad * 8);
        bf16x8 aV1 = *(const bf16x8*)(vb + (size_t)(col + 16) * SK_ + kc + quad * 8);

        f32x4 z = {0.f, 0.f, 0.f, 0.f};
        f32x4 s0 = __builtin_amdgcn_mfma_f32_16x16x32_bf16(aK0, bQ, z, 0, 0, 0);
        f32x4 s1 = __builtin_amdgcn_mfma_f32_16x16x32_bf16(aK1, bQ, z, 0, 0, 0);

        // P = exp(S); lane holds keys quad*4+reg (tile0), 16+quad*4+reg (tile1), q=col
        float p00 = __expf(s0[0]), p01 = __expf(s0[1]), p02 = __expf(s0[2]), p03 = __expf(s0[3]);
        float p10 = __expf(s1[0]), p11 = __expf(s1[1]), p12 = __expf(s1[2]), p13 = __expf(s1[3]);
        lsum += ((p00 + p01) + (p02 + p03)) + ((p10 + p11) + (p12 + p13));

        uint t0A = pack2(p00, p01), t0B = pack2(p02, p03);
        uint t1A = pack2(p10, p11), t1B = pack2(p12, p13);

        // permute C/D layout -> B-frag layout: lane(quad,col) needs keys 8*quad..+7, q=col
        int y0 = __shfl((int)t0A, sA, 64), y1 = __shfl((int)t1A, sA, 64);
        int y2 = __shfl((int)t0B, sA, 64), y3 = __shfl((int)t1B, sA, 64);
        int y4 = __shfl((int)t0A, sB, 64), y5 = __shfl((int)t1A, sB, 64);
        int y6 = __shfl((int)t0B, sB, 64), y7 = __shfl((int)t1B, sB, 64);
        uint4 bp;
        bp.x = lo ? (uint)y0 : (uint)y1;   // keys 8q+0,1
        bp.y = lo ? (uint)y2 : (uint)y3;   // keys 8q+2,3
        bp.z = lo ? (uint)y4 : (uint)y5;   // keys 8q+4,5
        bp.w = lo ? (uint)y6 : (uint)y7;   // keys 8q+6,7
        bf16x8 bP = __builtin_bit_cast(bf16x8, bp);

        // O^T += V^T . P   (D[c][q])
        acc0 = __builtin_amdgcn_mfma_f32_16x16x32_bf16(aV0, bP, acc0, 0, 0, 0);
        acc1 = __builtin_amdgcn_mfma_f32_16x16x32_bf16(aV1, bP, acc1, 0, 0, 0);
    }

    // l[q=col]: butterfly over quads (lanes col, col+16, col+32, col+48)
    lsum += __shfl_xor(lsum, 16, 64);
    lsum += __shfl_xor(lsum, 32, 64);
    const float inv = 1.f / lsum;

    const int n = nh >> 2, h = nh & 3;
    float* xo = x_ws + ((size_t)n * SQ_ + qbase + col) * INNER + h * HD;
    *(float4*)(xo + quad * 4)      = make_float4(acc0[0] * inv, acc0[1] * inv, acc0[2] * inv, acc0[3] * inv);
    *(float4*)(xo + 16 + quad * 4) = make_float4(acc1[0] * inv, acc1[1] * inv, acc1[2] * inv, acc1[3] * inv);
}

// ---------------------------------------------------------------------------
// Kernel 4: up-projection (fp32).  jj loop NOT unrolled (round-2: double
// unroll spilled -> 13 GB scratch traffic).
// ---------------------------------------------------------------------------
__global__ __launch_bounds__(256) void up_kernel(
    const float* __restrict__ x_ws, const float* __restrict__ Wup,
    float* __restrict__ out)
{
    const int s = blockIdx.x;
    __shared__ float xr[NB * INNER];           // 4 KB
    for (int i = threadIdx.x; i < NB * INNER; i += 256) {
        int n = i >> 7, j = i & 127;
        xr[i] = x_ws[((size_t)n * SQ_ + s) * INNER + j];
    }
    __syncthreads();

#pragma unroll 1
    for (int jj = 0; jj < 4; jj++) {
        const int d = (jj << 8) + threadIdx.x;
        const float4* w4 = (const float4*)(Wup + (size_t)d * INNER);
        float acc[NB];
#pragma unroll
        for (int n = 0; n < NB; n++) acc[n] = 0.f;
#pragma unroll 4
        for (int i = 0; i < INNER / 4; i++) {
            float4 w = w4[i];
#pragma unroll
            for (int n = 0; n < NB; n++) {
                float4 x = *(const float4*)&xr[n * INNER + i * 4];
                acc[n] = fmaf(w.x, x.x, fmaf(w.y, x.y, fmaf(w.z, x.z, fmaf(w.w, x.w, acc[n]))));
            }
        }
        float* orow = out + (size_t)s * NB * DD + d;
#pragma unroll
        for (int n = 0; n < NB; n++) orow[(size_t)n * DD] = acc[n];
    }
}

// ---------------------------------------------------------------------------
extern "C" void kernel_launch(void* const* d_in, const int* in_sizes, int n_in,
                              void* d_out, int out_size, void* d_ws, size_t ws_size,
                              hipStream_t stream)
{
    const float* query    = (const float*)d_in[0];
    const float* key_feat = (const float*)d_in[1];
    const float* Wq  = (const float*)d_in[2];
    const float* Wk  = (const float*)d_in[3];
    const float* Wv  = (const float*)d_in[4];
    const float* Wup = (const float*)d_in[5];
    float* out = (float*)d_out;

    ushort* ws16 = (ushort*)d_ws;
    const size_t SZ = (size_t)NB * H_ * 2048 * HD;   // 2,097,152 elems per tensor
    ushort* q_ws  = ws16;                            // bf16
    ushort* k_ws  = ws16 + SZ;                       // bf16
    ushort* v_ws  = ws16 + 2 * SZ;                   // bf16
    ushort* vt_ws = ws16 + 3 * SZ;                   // bf16, transposed
    float*  x_ws  = (float*)(ws16 + 4 * SZ);         // fp32

    proj_kernel<<<dim3(2048, 3), 128, 0, stream>>>(query, key_feat, Wq, Wk, Wv,
                                                   q_ws, k_ws, v_ws);
    vtrans_kernel<<<512, 256, 0, stream>>>(v_ws, vt_ws);
    attn_mfma<<<dim3(32, 32), 256, 0, stream>>>(q_ws, k_ws, vt_ws, x_ws);
    up_kernel<<<2048, 256, 0, stream>>>(x_ws, Wup, out);
}

// Round 5
// 429.034 us; speedup vs baseline: 26.6123x; 1.7911x over previous
//
#include <hip/hip_runtime.h>

typedef unsigned int uint;
typedef unsigned short ushort;
typedef float f32x4 __attribute__((ext_vector_type(4)));
typedef short bf16x8 __attribute__((ext_vector_type(8)));

#define SQ_   2048
#define SK_   2048
#define NB    8
#define DD    1024
#define INNER 128
#define H_    4
#define HD    32
// 1/sqrt(32), folded into Wq during wprep
#define ALPHA 0.17677669529663687f
#define PROW  136   // LDS X row: 128 bf16 + 8 pad (bank-uniform for b128 r/w)

__device__ __forceinline__ ushort f2bf(float f) {
    uint u = __float_as_uint(f);
    u += 0x7fffu + ((u >> 16) & 1u);
    return (ushort)(u >> 16);
}
__device__ __forceinline__ uint pack2(float a, float b) {
    return (uint)f2bf(a) | ((uint)f2bf(b) << 16);
}

// ---------------------------------------------------------------------------
// Kernel 0: convert Wq/Wk/Wv fp32 -> bf16 (ALPHA folded into Wq).
// wbf layout: [which][e][d], 3 x 128 x 1024.  192 blocks x 256 thr x 8 elems.
// ---------------------------------------------------------------------------
__global__ __launch_bounds__(256) void wprep_kernel(
    const float* __restrict__ Wq, const float* __restrict__ Wk, const float* __restrict__ Wv,
    ushort* __restrict__ wbf)
{
    int idx = (blockIdx.x * 256 + threadIdx.x) * 8;
    int which = idx >> 17;                       // /131072
    int off = idx & 131071;
    const float* W = (which == 0) ? Wq : (which == 1) ? Wk : Wv;
    const float sc = (which == 0) ? ALPHA : 1.0f;
    float4 a = *(const float4*)(W + off);
    float4 b = *(const float4*)(W + off + 4);
    uint4 o;
    o.x = pack2(a.x * sc, a.y * sc);
    o.y = pack2(a.z * sc, a.w * sc);
    o.z = pack2(b.x * sc, b.y * sc);
    o.w = pack2(b.z * sc, b.w * sc);
    *(uint4*)(wbf + idx) = o;
}

// ---------------------------------------------------------------------------
// Kernel 1: QKV projection via MFMA 16x16x32 bf16.
// Grid (256, 3): y selects {q,k,v}; x = 64-position tile.  Block = 4 waves;
// wave w owns head h=w (e in [32w,32w+32)).  M=128 x N=64 x K=1024.
// X fp32 staged->bf16 in LDS per 128-K slab; W read as bf16 frags from L2.
// Output: dst[((n*H+h)*2048+s)*32+c] bf16, p = s*8+n.
// ---------------------------------------------------------------------------
__global__ __launch_bounds__(256) void proj_mfma(
    const float* __restrict__ query, const float* __restrict__ key_feat,
    const ushort* __restrict__ wbf,
    ushort* __restrict__ q_ws, ushort* __restrict__ k_ws, ushort* __restrict__ v_ws)
{
    const int which = blockIdx.y;
    const float* src = (which == 0) ? query : key_feat;
    const ushort* W  = wbf + (size_t)which * (INNER * DD);
    ushort* dst      = (which == 0) ? q_ws : (which == 1) ? k_ws : v_ws;

    __shared__ ushort Xs[64 * PROW];             // 17408 B

    const int pblk = blockIdx.x;
    const int t = threadIdx.x;
    const int wave = t >> 6, lane = t & 63, quad = lane >> 4, col = lane & 15;

    // staging: thread -> (row sp, quarter sq of 32 d-elems)
    const int sp = t >> 2, sq = t & 3;
    const float* srow = src + (size_t)(pblk * 64 + sp) * DD + sq * 32;
    ushort* lrow = Xs + sp * PROW + sq * 32;

    f32x4 acc[2][4];
#pragma unroll
    for (int e = 0; e < 2; e++)
#pragma unroll
        for (int pt = 0; pt < 4; pt++) acc[e][pt] = (f32x4){0.f, 0.f, 0.f, 0.f};

    const ushort* wrow0 = W + (size_t)(32 * wave + col) * DD + quad * 8;
    const ushort* wrow1 = W + (size_t)(32 * wave + 16 + col) * DD + quad * 8;

    for (int slab = 0; slab < DD / 128; slab++) {
        const float4* g = (const float4*)(srow + slab * 128);
        float4 f0 = g[0], f1 = g[1], f2 = g[2], f3 = g[3];
        float4 f4 = g[4], f5 = g[5], f6 = g[6], f7 = g[7];
        __syncthreads();                         // prior slab's reads done
        uint4 u;
        u.x = pack2(f0.x, f0.y); u.y = pack2(f0.z, f0.w);
        u.z = pack2(f1.x, f1.y); u.w = pack2(f1.z, f1.w);
        *(uint4*)(lrow) = u;
        u.x = pack2(f2.x, f2.y); u.y = pack2(f2.z, f2.w);
        u.z = pack2(f3.x, f3.y); u.w = pack2(f3.z, f3.w);
        *(uint4*)(lrow + 8) = u;
        u.x = pack2(f4.x, f4.y); u.y = pack2(f4.z, f4.w);
        u.z = pack2(f5.x, f5.y); u.w = pack2(f5.z, f5.w);
        *(uint4*)(lrow + 16) = u;
        u.x = pack2(f6.x, f6.y); u.y = pack2(f6.z, f6.w);
        u.z = pack2(f7.x, f7.y); u.w = pack2(f7.z, f7.w);
        *(uint4*)(lrow + 24) = u;
        __syncthreads();

#pragma unroll
        for (int kk = 0; kk < 4; kk++) {
            bf16x8 aW0 = *(const bf16x8*)(wrow0 + slab * 128 + kk * 32);
            bf16x8 aW1 = *(const bf16x8*)(wrow1 + slab * 128 + kk * 32);
#pragma unroll
            for (int pt = 0; pt < 4; pt++) {
                bf16x8 bX = *(const bf16x8*)(Xs + (pt * 16 + col) * PROW + kk * 32 + quad * 8);
                acc[0][pt] = __builtin_amdgcn_mfma_f32_16x16x32_bf16(aW0, bX, acc[0][pt], 0, 0, 0);
                acc[1][pt] = __builtin_amdgcn_mfma_f32_16x16x32_bf16(aW1, bX, acc[1][pt], 0, 0, 0);
            }
        }
    }

    // store: D[m][n]: m -> c = etile*16 + quad*4 + reg (head h = wave), n -> p
#pragma unroll
    for (int pt = 0; pt < 4; pt++) {
        int p = pblk * 64 + pt * 16 + col;
        int s = p >> 3, n = p & 7;
        ushort* base = dst + ((size_t)(n * H_ + wave) * 2048 + s) * HD;
#pragma unroll
        for (int e = 0; e < 2; e++) {
            uint2 pk;
            pk.x = pack2(acc[e][pt][0], acc[e][pt][1]);
            pk.y = pack2(acc[e][pt][2], acc[e][pt][3]);
            *(uint2*)(base + e * 16 + quad * 4) = pk;
        }
    }
}

// ---------------------------------------------------------------------------
// Kernel 2: transpose V -> V^T.  v_ws[nh][key][32] bf16 -> vt_ws[nh][32][key].
// ---------------------------------------------------------------------------
__global__ __launch_bounds__(256) void vtrans_kernel(
    const ushort* __restrict__ v_ws, ushort* __restrict__ vt_ws)
{
    const int nh = blockIdx.x >> 4;
    const int slab = blockIdx.x & 15;
    __shared__ ushort t[HD][132];            // +4 pad
    const uint* src = (const uint*)(v_ws + ((size_t)nh * SK_ + slab * 128) * HD);
#pragma unroll
    for (int it = 0; it < 8; it++) {
        int i = it * 256 + threadIdx.x;      // 2048 uints = 128 keys x 16
        int key = i >> 4, j = i & 15;
        uint u = src[i];
        t[2 * j][key]     = (ushort)(u & 0xffffu);
        t[2 * j + 1][key] = (ushort)(u >> 16);
    }
    __syncthreads();
    uint* dst = (uint*)vt_ws;
#pragma unroll
    for (int it = 0; it < 8; it++) {
        int i = it * 256 + threadIdx.x;      // 2048 uints = 32 c x 64
        int c = i >> 6, kk = (i & 63) * 2;
        dst[(size_t)(nh * HD + c) * (SK_ / 2) + slab * 64 + (i & 63)] =
            (uint)t[c][kk] | ((uint)t[c][kk + 1] << 16);
    }
}

// ---------------------------------------------------------------------------
// Kernel 3: attention via MFMA 16x16x32 bf16 (unchanged from round 4).
// ---------------------------------------------------------------------------
__global__ __launch_bounds__(256) void attn_mfma(
    const ushort* __restrict__ q_ws, const ushort* __restrict__ k_ws,
    const ushort* __restrict__ vt_ws, float* __restrict__ x_ws)
{
    const int nh   = blockIdx.y;
    const int lane = threadIdx.x & 63;
    const int wave = threadIdx.x >> 6;
    const int quad = lane >> 4;
    const int col  = lane & 15;
    const int qbase = blockIdx.x * 64 + wave * 16;

    const bf16x8 bQ = *(const bf16x8*)(q_ws + ((size_t)nh * SQ_ + qbase + col) * HD + quad * 8);

    f32x4 acc0 = {0.f, 0.f, 0.f, 0.f};
    f32x4 acc1 = {0.f, 0.f, 0.f, 0.f};
    float lsum = 0.f;

    const ushort* kb = k_ws  + (size_t)nh * SK_ * HD;
    const ushort* vb = vt_ws + (size_t)nh * HD * SK_;
    const int sA = ((quad & 1) << 5) + col;
    const int sB = sA + 16;
    const bool lo = quad < 2;

#pragma unroll 2
    for (int kc = 0; kc < SK_; kc += 32) {
        bf16x8 aK0 = *(const bf16x8*)(kb + (size_t)(kc + col) * HD + quad * 8);
        bf16x8 aK1 = *(const bf16x8*)(kb + (size_t)(kc + 16 + col) * HD + quad * 8);
        bf16x8 aV0 = *(const bf16x8*)(vb + (size_t)col * SK_ + kc + quad * 8);
        bf16x8 aV1 = *(const bf16x8*)(vb + (size_t)(col + 16) * SK_ + kc + quad * 8);

        f32x4 z = {0.f, 0.f, 0.f, 0.f};
        f32x4 s0 = __builtin_amdgcn_mfma_f32_16x16x32_bf16(aK0, bQ, z, 0, 0, 0);
        f32x4 s1 = __builtin_amdgcn_mfma_f32_16x16x32_bf16(aK1, bQ, z, 0, 0, 0);

        float p00 = __expf(s0[0]), p01 = __expf(s0[1]), p02 = __expf(s0[2]), p03 = __expf(s0[3]);
        float p10 = __expf(s1[0]), p11 = __expf(s1[1]), p12 = __expf(s1[2]), p13 = __expf(s1[3]);
        lsum += ((p00 + p01) + (p02 + p03)) + ((p10 + p11) + (p12 + p13));

        uint t0A = pack2(p00, p01), t0B = pack2(p02, p03);
        uint t1A = pack2(p10, p11), t1B = pack2(p12, p13);

        int y0 = __shfl((int)t0A, sA, 64), y1 = __shfl((int)t1A, sA, 64);
        int y2 = __shfl((int)t0B, sA, 64), y3 = __shfl((int)t1B, sA, 64);
        int y4 = __shfl((int)t0A, sB, 64), y5 = __shfl((int)t1A, sB, 64);
        int y6 = __shfl((int)t0B, sB, 64), y7 = __shfl((int)t1B, sB, 64);
        uint4 bp;
        bp.x = lo ? (uint)y0 : (uint)y1;
        bp.y = lo ? (uint)y2 : (uint)y3;
        bp.z = lo ? (uint)y4 : (uint)y5;
        bp.w = lo ? (uint)y6 : (uint)y7;
        bf16x8 bP = __builtin_bit_cast(bf16x8, bp);

        acc0 = __builtin_amdgcn_mfma_f32_16x16x32_bf16(aV0, bP, acc0, 0, 0, 0);
        acc1 = __builtin_amdgcn_mfma_f32_16x16x32_bf16(aV1, bP, acc1, 0, 0, 0);
    }

    lsum += __shfl_xor(lsum, 16, 64);
    lsum += __shfl_xor(lsum, 32, 64);
    const float inv = 1.f / lsum;

    const int n = nh >> 2, h = nh & 3;
    float* xo = x_ws + ((size_t)n * SQ_ + qbase + col) * INNER + h * HD;
    *(float4*)(xo + quad * 4)      = make_float4(acc0[0] * inv, acc0[1] * inv, acc0[2] * inv, acc0[3] * inv);
    *(float4*)(xo + 16 + quad * 4) = make_float4(acc1[0] * inv, acc1[1] * inv, acc1[2] * inv, acc1[3] * inv);
}

// ---------------------------------------------------------------------------
// Kernel 4: up-projection (fp32).  jj loop NOT unrolled (round-2 spill lesson).
// ---------------------------------------------------------------------------
__global__ __launch_bounds__(256) void up_kernel(
    const float* __restrict__ x_ws, const float* __restrict__ Wup,
    float* __restrict__ out)
{
    const int s = blockIdx.x;
    __shared__ float xr[NB * INNER];           // 4 KB
    for (int i = threadIdx.x; i < NB * INNER; i += 256) {
        int n = i >> 7, j = i & 127;
        xr[i] = x_ws[((size_t)n * SQ_ + s) * INNER + j];
    }
    __syncthreads();

#pragma unroll 1
    for (int jj = 0; jj < 4; jj++) {
        const int d = (jj << 8) + threadIdx.x;
        const float4* w4 = (const float4*)(Wup + (size_t)d * INNER);
        float acc[NB];
#pragma unroll
        for (int n = 0; n < NB; n++) acc[n] = 0.f;
#pragma unroll 4
        for (int i = 0; i < INNER / 4; i++) {
            float4 w = w4[i];
#pragma unroll
            for (int n = 0; n < NB; n++) {
                float4 x = *(const float4*)&xr[n * INNER + i * 4];
                acc[n] = fmaf(w.x, x.x, fmaf(w.y, x.y, fmaf(w.z, x.z, fmaf(w.w, x.w, acc[n]))));
            }
        }
        float* orow = out + (size_t)s * NB * DD + d;
#pragma unroll
        for (int n = 0; n < NB; n++) orow[(size_t)n * DD] = acc[n];
    }
}

// ---------------------------------------------------------------------------
extern "C" void kernel_launch(void* const* d_in, const int* in_sizes, int n_in,
                              void* d_out, int out_size, void* d_ws, size_t ws_size,
                              hipStream_t stream)
{
    const float* query    = (const float*)d_in[0];
    const float* key_feat = (const float*)d_in[1];
    const float* Wq  = (const float*)d_in[2];
    const float* Wk  = (const float*)d_in[3];
    const float* Wv  = (const float*)d_in[4];
    const float* Wup = (const float*)d_in[5];
    float* out = (float*)d_out;

    ushort* ws16 = (ushort*)d_ws;
    const size_t SZ = (size_t)NB * H_ * 2048 * HD;   // 2,097,152 elems per tensor
    ushort* q_ws  = ws16;                            // bf16
    ushort* k_ws  = ws16 + SZ;                       // bf16
    ushort* v_ws  = ws16 + 2 * SZ;                   // bf16
    ushort* vt_ws = ws16 + 3 * SZ;                   // bf16, transposed
    ushort* wbf   = vt_ws;                           // aliased: wprep/proj use it
                                                     // BEFORE vtrans overwrites
    float*  x_ws  = (float*)(ws16 + 4 * SZ);         // fp32

    wprep_kernel<<<192, 256, 0, stream>>>(Wq, Wk, Wv, wbf);
    proj_mfma<<<dim3(256, 3), 256, 0, stream>>>(query, key_feat, wbf,
                                                q_ws, k_ws, v_ws);
    vtrans_kernel<<<512, 256, 0, stream>>>(v_ws, vt_ws);
    attn_mfma<<<dim3(32, 32), 256, 0, stream>>>(q_ws, k_ws, vt_ws, x_ws);
    up_kernel<<<2048, 256, 0, stream>>>(x_ws, Wup, out);
}

// Round 6
// 333.384 us; speedup vs baseline: 34.2475x; 1.2869x over previous
//
#include <hip/hip_runtime.h>

typedef unsigned int uint;
typedef unsigned short ushort;
typedef float f32x4 __attribute__((ext_vector_type(4)));
typedef short bf16x8 __attribute__((ext_vector_type(8)));

#define SQ_   2048
#define SK_   2048
#define NB    8
#define DD    1024
#define INNER 128
#define H_    4
#define HD    32
// 1/sqrt(32), folded into Wq during wprep
#define ALPHA 0.17677669529663687f
#define PROW  136   // LDS X row: 128 bf16 + 8 pad (bank-uniform for b128 r/w)

__device__ __forceinline__ ushort f2bf(float f) {
    uint u = __float_as_uint(f);
    u += 0x7fffu + ((u >> 16) & 1u);
    return (ushort)(u >> 16);
}
__device__ __forceinline__ uint pack2(float a, float b) {
    return (uint)f2bf(a) | ((uint)f2bf(b) << 16);
}

// ---------------------------------------------------------------------------
// Kernel 0: convert Wq/Wk/Wv -> wbf (ALPHA folded into Wq) and Wup -> wup_bf.
// 256 blocks x 256 thr x 8 elems = 524288 elems (393216 qkv + 131072 wup).
// ---------------------------------------------------------------------------
__global__ __launch_bounds__(256) void wprep_kernel(
    const float* __restrict__ Wq, const float* __restrict__ Wk,
    const float* __restrict__ Wv, const float* __restrict__ Wup,
    ushort* __restrict__ wbf, ushort* __restrict__ wup_bf)
{
    int idx = (blockIdx.x * 256 + threadIdx.x) * 8;
    const float* W;
    ushort* dst;
    float sc = 1.0f;
    int off;
    if (idx < 393216) {
        int which = idx >> 17;                   // /131072
        off = idx & 131071;
        W = (which == 0) ? Wq : (which == 1) ? Wk : Wv;
        if (which == 0) sc = ALPHA;
        dst = wbf + idx;
    } else {
        off = idx - 393216;
        W = Wup;
        dst = wup_bf + off;
    }
    float4 a = *(const float4*)(W + off);
    float4 b = *(const float4*)(W + off + 4);
    uint4 o;
    o.x = pack2(a.x * sc, a.y * sc);
    o.y = pack2(a.z * sc, a.w * sc);
    o.z = pack2(b.x * sc, b.y * sc);
    o.w = pack2(b.z * sc, b.w * sc);
    *(uint4*)dst = o;
}

// ---------------------------------------------------------------------------
// Kernel 1: QKV projection via MFMA 16x16x32 bf16 (unchanged from round 5).
// Output: dst[((n*H+h)*2048+s)*32+c] bf16, p = s*8+n.
// ---------------------------------------------------------------------------
__global__ __launch_bounds__(256) void proj_mfma(
    const float* __restrict__ query, const float* __restrict__ key_feat,
    const ushort* __restrict__ wbf,
    ushort* __restrict__ q_ws, ushort* __restrict__ k_ws, ushort* __restrict__ v_ws)
{
    const int which = blockIdx.y;
    const float* src = (which == 0) ? query : key_feat;
    const ushort* W  = wbf + (size_t)which * (INNER * DD);
    ushort* dst      = (which == 0) ? q_ws : (which == 1) ? k_ws : v_ws;

    __shared__ ushort Xs[64 * PROW];             // 17408 B

    const int pblk = blockIdx.x;
    const int t = threadIdx.x;
    const int wave = t >> 6, lane = t & 63, quad = lane >> 4, col = lane & 15;

    const int sp = t >> 2, sq = t & 3;
    const float* srow = src + (size_t)(pblk * 64 + sp) * DD + sq * 32;
    ushort* lrow = Xs + sp * PROW + sq * 32;

    f32x4 acc[2][4];
#pragma unroll
    for (int e = 0; e < 2; e++)
#pragma unroll
        for (int pt = 0; pt < 4; pt++) acc[e][pt] = (f32x4){0.f, 0.f, 0.f, 0.f};

    const ushort* wrow0 = W + (size_t)(32 * wave + col) * DD + quad * 8;
    const ushort* wrow1 = W + (size_t)(32 * wave + 16 + col) * DD + quad * 8;

    for (int slab = 0; slab < DD / 128; slab++) {
        const float4* g = (const float4*)(srow + slab * 128);
        float4 f0 = g[0], f1 = g[1], f2 = g[2], f3 = g[3];
        float4 f4 = g[4], f5 = g[5], f6 = g[6], f7 = g[7];
        __syncthreads();                         // prior slab's reads done
        uint4 u;
        u.x = pack2(f0.x, f0.y); u.y = pack2(f0.z, f0.w);
        u.z = pack2(f1.x, f1.y); u.w = pack2(f1.z, f1.w);
        *(uint4*)(lrow) = u;
        u.x = pack2(f2.x, f2.y); u.y = pack2(f2.z, f2.w);
        u.z = pack2(f3.x, f3.y); u.w = pack2(f3.z, f3.w);
        *(uint4*)(lrow + 8) = u;
        u.x = pack2(f4.x, f4.y); u.y = pack2(f4.z, f4.w);
        u.z = pack2(f5.x, f5.y); u.w = pack2(f5.z, f5.w);
        *(uint4*)(lrow + 16) = u;
        u.x = pack2(f6.x, f6.y); u.y = pack2(f6.z, f6.w);
        u.z = pack2(f7.x, f7.y); u.w = pack2(f7.z, f7.w);
        *(uint4*)(lrow + 24) = u;
        __syncthreads();

#pragma unroll
        for (int kk = 0; kk < 4; kk++) {
            bf16x8 aW0 = *(const bf16x8*)(wrow0 + slab * 128 + kk * 32);
            bf16x8 aW1 = *(const bf16x8*)(wrow1 + slab * 128 + kk * 32);
#pragma unroll
            for (int pt = 0; pt < 4; pt++) {
                bf16x8 bX = *(const bf16x8*)(Xs + (pt * 16 + col) * PROW + kk * 32 + quad * 8);
                acc[0][pt] = __builtin_amdgcn_mfma_f32_16x16x32_bf16(aW0, bX, acc[0][pt], 0, 0, 0);
                acc[1][pt] = __builtin_amdgcn_mfma_f32_16x16x32_bf16(aW1, bX, acc[1][pt], 0, 0, 0);
            }
        }
    }

#pragma unroll
    for (int pt = 0; pt < 4; pt++) {
        int p = pblk * 64 + pt * 16 + col;
        int s = p >> 3, n = p & 7;
        ushort* base = dst + ((size_t)(n * H_ + wave) * 2048 + s) * HD;
#pragma unroll
        for (int e = 0; e < 2; e++) {
            uint2 pk;
            pk.x = pack2(acc[e][pt][0], acc[e][pt][1]);
            pk.y = pack2(acc[e][pt][2], acc[e][pt][3]);
            *(uint2*)(base + e * 16 + quad * 4) = pk;
        }
    }
}

// ---------------------------------------------------------------------------
// Kernel 2: transpose V -> V^T.  v_ws[nh][key][32] bf16 -> vt_ws[nh][32][key].
// ---------------------------------------------------------------------------
__global__ __launch_bounds__(256) void vtrans_kernel(
    const ushort* __restrict__ v_ws, ushort* __restrict__ vt_ws)
{
    const int nh = blockIdx.x >> 4;
    const int slab = blockIdx.x & 15;
    __shared__ ushort t[HD][132];            // +4 pad
    const uint* src = (const uint*)(v_ws + ((size_t)nh * SK_ + slab * 128) * HD);
#pragma unroll
    for (int it = 0; it < 8; it++) {
        int i = it * 256 + threadIdx.x;      // 2048 uints = 128 keys x 16
        int key = i >> 4, j = i & 15;
        uint u = src[i];
        t[2 * j][key]     = (ushort)(u & 0xffffu);
        t[2 * j + 1][key] = (ushort)(u >> 16);
    }
    __syncthreads();
    uint* dst = (uint*)vt_ws;
#pragma unroll
    for (int it = 0; it < 8; it++) {
        int i = it * 256 + threadIdx.x;      // 2048 uints = 32 c x 64
        int c = i >> 6, kk = (i & 63) * 2;
        dst[(size_t)(nh * HD + c) * (SK_ / 2) + slab * 64 + (i & 63)] =
            (uint)t[c][kk] | ((uint)t[c][kk + 1] << 16);
    }
}

// ---------------------------------------------------------------------------
// Kernel 3: attention via MFMA 16x16x32 bf16.  x_ws output now bf16.
// ---------------------------------------------------------------------------
__global__ __launch_bounds__(256) void attn_mfma(
    const ushort* __restrict__ q_ws, const ushort* __restrict__ k_ws,
    const ushort* __restrict__ vt_ws, ushort* __restrict__ x_ws)
{
    const int nh   = blockIdx.y;
    const int lane = threadIdx.x & 63;
    const int wave = threadIdx.x >> 6;
    const int quad = lane >> 4;
    const int col  = lane & 15;
    const int qbase = blockIdx.x * 64 + wave * 16;

    const bf16x8 bQ = *(const bf16x8*)(q_ws + ((size_t)nh * SQ_ + qbase + col) * HD + quad * 8);

    f32x4 acc0 = {0.f, 0.f, 0.f, 0.f};
    f32x4 acc1 = {0.f, 0.f, 0.f, 0.f};
    float lsum = 0.f;

    const ushort* kb = k_ws  + (size_t)nh * SK_ * HD;
    const ushort* vb = vt_ws + (size_t)nh * HD * SK_;
    const int sA = ((quad & 1) << 5) + col;
    const int sB = sA + 16;
    const bool lo = quad < 2;

#pragma unroll 2
    for (int kc = 0; kc < SK_; kc += 32) {
        bf16x8 aK0 = *(const bf16x8*)(kb + (size_t)(kc + col) * HD + quad * 8);
        bf16x8 aK1 = *(const bf16x8*)(kb + (size_t)(kc + 16 + col) * HD + quad * 8);
        bf16x8 aV0 = *(const bf16x8*)(vb + (size_t)col * SK_ + kc + quad * 8);
        bf16x8 aV1 = *(const bf16x8*)(vb + (size_t)(col + 16) * SK_ + kc + quad * 8);

        f32x4 z = {0.f, 0.f, 0.f, 0.f};
        f32x4 s0 = __builtin_amdgcn_mfma_f32_16x16x32_bf16(aK0, bQ, z, 0, 0, 0);
        f32x4 s1 = __builtin_amdgcn_mfma_f32_16x16x32_bf16(aK1, bQ, z, 0, 0, 0);

        float p00 = __expf(s0[0]), p01 = __expf(s0[1]), p02 = __expf(s0[2]), p03 = __expf(s0[3]);
        float p10 = __expf(s1[0]), p11 = __expf(s1[1]), p12 = __expf(s1[2]), p13 = __expf(s1[3]);
        lsum += ((p00 + p01) + (p02 + p03)) + ((p10 + p11) + (p12 + p13));

        uint t0A = pack2(p00, p01), t0B = pack2(p02, p03);
        uint t1A = pack2(p10, p11), t1B = pack2(p12, p13);

        int y0 = __shfl((int)t0A, sA, 64), y1 = __shfl((int)t1A, sA, 64);
        int y2 = __shfl((int)t0B, sA, 64), y3 = __shfl((int)t1B, sA, 64);
        int y4 = __shfl((int)t0A, sB, 64), y5 = __shfl((int)t1A, sB, 64);
        int y6 = __shfl((int)t0B, sB, 64), y7 = __shfl((int)t1B, sB, 64);
        uint4 bp;
        bp.x = lo ? (uint)y0 : (uint)y1;
        bp.y = lo ? (uint)y2 : (uint)y3;
        bp.z = lo ? (uint)y4 : (uint)y5;
        bp.w = lo ? (uint)y6 : (uint)y7;
        bf16x8 bP = __builtin_bit_cast(bf16x8, bp);

        acc0 = __builtin_amdgcn_mfma_f32_16x16x32_bf16(aV0, bP, acc0, 0, 0, 0);
        acc1 = __builtin_amdgcn_mfma_f32_16x16x32_bf16(aV1, bP, acc1, 0, 0, 0);
    }

    lsum += __shfl_xor(lsum, 16, 64);
    lsum += __shfl_xor(lsum, 32, 64);
    const float inv = 1.f / lsum;

    const int n = nh >> 2, h = nh & 3;
    ushort* xo = x_ws + ((size_t)n * SQ_ + qbase + col) * INNER + h * HD;
    uint2 pk0, pk1;
    pk0.x = pack2(acc0[0] * inv, acc0[1] * inv);
    pk0.y = pack2(acc0[2] * inv, acc0[3] * inv);
    pk1.x = pack2(acc1[0] * inv, acc1[1] * inv);
    pk1.y = pack2(acc1[2] * inv, acc1[3] * inv);
    *(uint2*)(xo + quad * 4)      = pk0;
    *(uint2*)(xo + 16 + quad * 4) = pk1;
}

// ---------------------------------------------------------------------------
// Kernel 4: up-projection via MFMA 16x16x32 bf16 (replaces fp32 up_kernel —
// round-5: fp32 VALU version was 167 us, latency/VALU-bound).
// GEMM: out[p][d] = sum_e x[p][e] * Wup[d][e];  M=d, N=p, K=128.
// Block = 4 waves = 64 p x 64 d; wave owns 16 p, loops 4 d-tiles x 4 K-chunks.
// A-frag = Wup row (16B contiguous), B-frag = x row (16B contiguous), no LDS.
// Store: D[m=d][n=p]; 4 quads of a col write one 64 B line of out row s*8+n.
// ---------------------------------------------------------------------------
__global__ __launch_bounds__(256) void up_mfma(
    const ushort* __restrict__ x_ws, const ushort* __restrict__ wup_bf,
    float* __restrict__ out)
{
    const int pblk = blockIdx.x;
    const int dblk = blockIdx.y;
    const int wave = threadIdx.x >> 6, lane = threadIdx.x & 63;
    const int quad = lane >> 4, col = lane & 15;

    const int p0 = pblk * 64 + wave * 16;
    const ushort* xrow = x_ws + (size_t)(p0 + col) * INNER + quad * 8;
    bf16x8 bX[4];
#pragma unroll
    for (int kk = 0; kk < 4; kk++)
        bX[kk] = *(const bf16x8*)(xrow + kk * 32);

    const int p = p0 + col;
    const int n = p >> 11, s = p & 2047;        // x row p = n*2048 + s
    float* obase = out + ((size_t)s * NB + n) * DD;

#pragma unroll
    for (int mt = 0; mt < 4; mt++) {
        const int d0 = dblk * 64 + mt * 16;
        const ushort* wrow = wup_bf + (size_t)(d0 + col) * INNER + quad * 8;
        f32x4 acc = {0.f, 0.f, 0.f, 0.f};
#pragma unroll
        for (int kk = 0; kk < 4; kk++) {
            bf16x8 aW = *(const bf16x8*)(wrow + kk * 32);
            acc = __builtin_amdgcn_mfma_f32_16x16x32_bf16(aW, bX[kk], acc, 0, 0, 0);
        }
        *(float4*)(obase + d0 + quad * 4) = make_float4(acc[0], acc[1], acc[2], acc[3]);
    }
}

// ---------------------------------------------------------------------------
extern "C" void kernel_launch(void* const* d_in, const int* in_sizes, int n_in,
                              void* d_out, int out_size, void* d_ws, size_t ws_size,
                              hipStream_t stream)
{
    const float* query    = (const float*)d_in[0];
    const float* key_feat = (const float*)d_in[1];
    const float* Wq  = (const float*)d_in[2];
    const float* Wk  = (const float*)d_in[3];
    const float* Wv  = (const float*)d_in[4];
    const float* Wup = (const float*)d_in[5];
    float* out = (float*)d_out;

    ushort* ws16 = (ushort*)d_ws;
    const size_t SZ = (size_t)NB * H_ * 2048 * HD;   // 2,097,152 elems per tensor
    ushort* q_ws   = ws16;                           // bf16
    ushort* k_ws   = ws16 + SZ;                      // bf16
    ushort* v_ws   = ws16 + 2 * SZ;                  // bf16
    ushort* vt_ws  = ws16 + 3 * SZ;                  // bf16, transposed
    ushort* wbf    = vt_ws;                          // aliased: consumed by proj
                                                     // BEFORE vtrans overwrites
    ushort* x_ws   = ws16 + 4 * SZ;                  // bf16 now
    ushort* wup_bf = ws16 + 5 * SZ;                  // bf16, never aliased

    wprep_kernel<<<256, 256, 0, stream>>>(Wq, Wk, Wv, Wup, wbf, wup_bf);
    proj_mfma<<<dim3(256, 3), 256, 0, stream>>>(query, key_feat, wbf,
                                                q_ws, k_ws, v_ws);
    vtrans_kernel<<<512, 256, 0, stream>>>(v_ws, vt_ws);
    attn_mfma<<<dim3(32, 32), 256, 0, stream>>>(q_ws, k_ws, vt_ws, x_ws);
    up_mfma<<<dim3(256, 16), 256, 0, stream>>>(x_ws, wup_bf, out);
}